// Round 3
// baseline (236.553 us; speedup 1.0000x reference)
//
#include <hip/hip_runtime.h>

#define HEADS 8
#define DHEAD 40
#define SEQ   4096
#define BATCH 2
#define INNER 320
#define NBH   16
// softmax scale * log2(e), folded into Wq so p = exp2(s) is a single v_exp_f32
#define QSCALE ((float)(0.15811388300841897 * 1.4426950408889634))

typedef _Float16 f16;
typedef __attribute__((ext_vector_type(2)))  __fp16   fp16x2;  // cvt_pkrtz native type
typedef __attribute__((ext_vector_type(4)))  _Float16 half4;
typedef __attribute__((ext_vector_type(8)))  _Float16 half8;
typedef __attribute__((ext_vector_type(16))) float    f32x16;

#if __has_builtin(__builtin_amdgcn_exp2f)
#define EXP2F(x) __builtin_amdgcn_exp2f(x)
#else
#define EXP2F(x) exp2f(x)
#endif

#define MFMA16(a, b, c) __builtin_amdgcn_mfma_f32_32x32x16_f16(a, b, c, 0, 0, 0)

union H8 { half8 h8; fp16x2 p2[4]; uint4 u4; };

// ---------------------------------------------------------------------------
// Convert fp32 inputs to f16 once: x -> xh [8192][320]; Wq|Wk|Wv -> wh
// [960][320] (Wq pre-scaled by QSCALE); Wout -> wouth [320][320].
// ---------------------------------------------------------------------------
#define XN4   (BATCH * SEQ * INNER / 4)   // 655360
#define WQKV4 (3 * INNER * INNER / 4)     // 76800
#define WOUT4 (INNER * INNER / 4)         // 25600
#define CONV_TOTAL (XN4 + WQKV4 + WOUT4)  // 757760

__global__ __launch_bounds__(256)
void convert_kernel(const float* __restrict__ x,
                    const float* __restrict__ Wq,
                    const float* __restrict__ Wk,
                    const float* __restrict__ Wv,
                    const float* __restrict__ Wout,
                    f16* __restrict__ xh, f16* __restrict__ wh,
                    f16* __restrict__ wouth)
{
    int i = blockIdx.x * 256 + threadIdx.x;
    if (i >= CONV_TOTAL) return;
    float4 v;
    f16* dst;
    float sc = 1.0f;
    if (i < XN4) {
        v = ((const float4*)x)[i];
        dst = xh + 4 * (size_t)i;
    } else if (i < XN4 + WQKV4) {
        int j = i - XN4;                       // float4 idx in concat [960][320]
        if (j < 25600)      { v = ((const float4*)Wq)[j]; sc = QSCALE; }
        else if (j < 51200) { v = ((const float4*)Wk)[j - 25600]; }
        else                { v = ((const float4*)Wv)[j - 51200]; }
        dst = wh + 4 * (size_t)j;
    } else {
        int j = i - XN4 - WQKV4;
        v = ((const float4*)Wout)[j];
        dst = wouth + 4 * (size_t)j;
    }
    H8 u;
    u.p2[0] = __builtin_amdgcn_cvt_pkrtz(v.x * sc, v.y * sc);
    u.p2[1] = __builtin_amdgcn_cvt_pkrtz(v.z * sc, v.w * sc);
    *(uint2*)dst = make_uint2(u.u4.x, u.u4.y);
}

// ---------------------------------------------------------------------------
// Merged QKV projection, fp16 MFMA. m-tile 64 x n-tile 192. Grid (5,128).
// v3: next-k-step global->reg prefetch so staging latency hides under MFMA.
// ---------------------------------------------------------------------------
#define QSTR 72

__global__ __launch_bounds__(256)
void qkv_gemm_kernel(const f16* __restrict__ xh, const f16* __restrict__ wh,
                     f16* __restrict__ q, f16* __restrict__ k,
                     f16* __restrict__ vt)
{
    __shared__ f16 lds[(64 + 192) * QSTR];   // As [64][72] + Bs [192][72] = 36864 B
    f16* As = lds;
    f16* Bs = lds + 64 * QSTR;

    const int tid = threadIdx.x;
    const int nb0 = blockIdx.x * 64;
    const int m0  = blockIdx.y * 64;
    const int wave = tid >> 6, lane = tid & 63, m = lane & 31, half = lane >> 5;
    const int mw = wave >> 1, nw = wave & 1;

    // staging indices (constant)
    const int ar = tid >> 3, ac8 = tid & 7;                    // A: 512 uint4, 2/thread
    const int ar1 = (256 + tid) >> 3;
    int br[6], bwr[6];                                         // B: 1536 uint4, 6/thread
    #pragma unroll
    for (int u = 0; u < 6; u++) {
        int idx = tid + 256 * u;
        int r = idx >> 3;
        br[u] = r;
        bwr[u] = (r >> 6) * 320 + nb0 + (r & 63);
    }

    f32x16 acc[3];
    #pragma unroll
    for (int i = 0; i < 16; i++) { acc[0][i] = 0.f; acc[1][i] = 0.f; acc[2][i] = 0.f; }

    // prefetch k0 = 0
    uint4 pa0, pa1, pb[6];
    pa0 = *(const uint4*)&xh[(size_t)(m0 + ar)  * 320 + ac8 * 8];
    pa1 = *(const uint4*)&xh[(size_t)(m0 + ar1) * 320 + ac8 * 8];
    #pragma unroll
    for (int u = 0; u < 6; u++)
        pb[u] = *(const uint4*)&wh[(size_t)bwr[u] * 320 + ac8 * 8];

    for (int k0 = 0; k0 < 320; k0 += 64) {
        __syncthreads();
        *(uint4*)&As[ar  * QSTR + ac8 * 8] = pa0;
        *(uint4*)&As[ar1 * QSTR + ac8 * 8] = pa1;
        #pragma unroll
        for (int u = 0; u < 6; u++)
            *(uint4*)&Bs[br[u] * QSTR + ac8 * 8] = pb[u];
        __syncthreads();

        if (k0 + 64 < 320) {
            pa0 = *(const uint4*)&xh[(size_t)(m0 + ar)  * 320 + k0 + 64 + ac8 * 8];
            pa1 = *(const uint4*)&xh[(size_t)(m0 + ar1) * 320 + k0 + 64 + ac8 * 8];
            #pragma unroll
            for (int u = 0; u < 6; u++)
                pb[u] = *(const uint4*)&wh[(size_t)bwr[u] * 320 + k0 + 64 + ac8 * 8];
        }

        #pragma unroll
        for (int c = 0; c < 4; c++) {
            half8 a = *(const half8*)&As[(mw * 32 + m) * QSTR + c * 16 + half * 8];
            #pragma unroll
            for (int t = 0; t < 3; t++) {
                half8 bf = *(const half8*)&Bs[(nw * 96 + t * 32 + m) * QSTR + c * 16 + half * 8];
                acc[t] = MFMA16(a, bf, acc[t]);
            }
        }
    }

    const int b = m0 >> 12, s0 = m0 & 4095;

    // q / k scatter (subtiles st = nw*3+t < 4)
    #pragma unroll
    for (int t = 0; t < 3; t++) {
        int st = nw * 3 + t;
        if (st < 4) {
            f16* dst = (st < 2) ? q : k;
            int col = nb0 + (st & 1) * 32 + m;
            int h  = (col * 205) >> 13;          // == col/40 for col<328
            int dd = col - h * 40;
            #pragma unroll
            for (int reg = 0; reg < 16; reg++) {
                int crow = 4 * half + (reg & 3) + 8 * (reg >> 2);
                int mg = m0 + mw * 32 + crow;
                int bb = mg >> 12, s = mg & 4095;
                dst[((size_t)(bb * 8 + h) * SEQ + s) * DHEAD + dd] = (f16)acc[t][reg];
            }
        }
    }

    // v transpose: subtiles st 4,5 (nw==1, t=1,2) -> Ct [64 vcol][72]
    __syncthreads();
    f16* Ct = lds;
    if (nw == 1) {
        #pragma unroll
        for (int t = 1; t < 3; t++) {
            int vr0 = (t - 1) * 32 + m;
            #pragma unroll
            for (int g = 0; g < 4; g++) {
                half4 hh;
                hh.x = (f16)acc[t][4 * g + 0]; hh.y = (f16)acc[t][4 * g + 1];
                hh.z = (f16)acc[t][4 * g + 2]; hh.w = (f16)acc[t][4 * g + 3];
                *(half4*)&Ct[vr0 * QSTR + mw * 32 + 8 * g + 4 * half] = hh;
            }
        }
    }
    __syncthreads();
    #pragma unroll
    for (int u = 0; u < 4; u++) {            // 64 rl x 16 c4 = 1024 uint2
        int idx = tid + 256 * u;
        int rl = idx >> 4, c4 = idx & 15;
        int col = nb0 + rl;
        int h  = (col * 205) >> 13;
        int dd = col - h * 40;
        int w4 = c4 & 3;
        int c4p = (c4 & ~3) | ((w4 == 1) ? 2 : (w4 == 2) ? 1 : w4);
        *(uint2*)&vt[((size_t)(b * 8 + h) * DHEAD + dd) * SEQ + s0 + c4p * 4] =
            *(const uint2*)&Ct[rl * QSTR + c4 * 4];
    }
}

// ---------------------------------------------------------------------------
// Flash attention, fp16 MFMA, P in registers (S^T trick).
// v3: 128 keys per barrier, processed as two independent 64-key subtiles
// A/B inside each wave. Rationale (r0/r1/r2 post-mortems): VALUBusy was
// invariant ~36.5% across three structures -> v_exp_f32 ~16 cyc/wave64;
// per-iter serial chain [ds -> S-MFMA -> 512-cyc exp -> PV] left all pipes
// <40% busy. With A/B in flight the compiler can issue S(B) MFMAs during
// exp(A) and PV(A) during exp(B): MFMA pipe overlaps the TRANS phase.
// LDS per buffer 32KB: K [128 keys][64h] chunk-swizzled 8*(c^(r&7)) with
// chunk 5 = zero pad (covers q d40..47); V [64 d-rows][128 keys] same
// swizzle, rows 40..63 pad (row 40 = ones -> row sums). Double-buffered,
// ONE barrier per 128 keys (WAR-safe: a full barrier + lgkm-forced read
// completion separates buf-x reads from its next overwrite 2 iters later).
// Epilogue: key-half partials combine exactly in LDS f32, normalize.
// ---------------------------------------------------------------------------
__global__ __launch_bounds__(256, 2)
void attn_kernel(const f16* __restrict__ q, const f16* __restrict__ k,
                 const f16* __restrict__ vt, f16* __restrict__ y)
{
    // 2 x 32768B staging buffers | epilogue f32 [128][66] = 33792B (union)
    __shared__ __align__(16) unsigned char ldsbuf[65536];
    f16*   ldsh = (f16*)ldsbuf;
    float* ldsf = (float*)ldsbuf;

    const int tid = threadIdx.x;
    const int blk = blockIdx.x;
    const int xcd = blk & 7, slot = blk >> 3;        // XCD swizzle: 2 bh per XCD
    const int bh = xcd * 2 + (slot >> 5), qt = slot & 31;
    const int b = bh >> 3, h = bh & 7;
    const int q0 = qt * 128;
    const int wave = tid >> 6, lane = tid & 63, m = lane & 31, half = lane >> 5;
    const int qp = wave >> 1, kh = wave & 1;
    const int x7 = m & 7;

    // ---- one-time pads (swizzled slots, both buffers)
    {   // K chunk 5 = 0 : 2 bufs x 128 rows = 256 writes
        int bsel = tid >> 7, r = tid & 127;
        *(uint4*)&ldsh[bsel * 16384 + r * 64 + 8 * (5 ^ (r & 7))] = make_uint4(0, 0, 0, 0);
    }
    #pragma unroll
    for (int u = 0; u < 3; u++) {                    // V rows 40..63: 2x24x16 = 768
        int idx = tid + 256 * u;
        int bsel = (idx >= 384) ? 1 : 0;
        int j = idx - bsel * 384;
        int r = 40 + (j >> 4), c = j & 15;
        uint4 val = (r == 40) ? make_uint4(0x3C003C00u, 0x3C003C00u, 0x3C003C00u, 0x3C003C00u)
                              : make_uint4(0, 0, 0, 0);
        *(uint4*)&ldsh[bsel * 16384 + 8192 + r * 128 + 8 * (c ^ (r & 7))] = val;
    }

    half8 zero8;
    #pragma unroll
    for (int j = 0; j < 8; j++) zero8[j] = (f16)0.0f;

    // ---- Q B-fragments for both q-subtiles (d 40..47 -> 0)
    half8 qa[2][3];
    {
        const f16* qb = q + ((size_t)bh * SEQ + q0 + qp * 64 + m) * DHEAD;
        #pragma unroll
        for (int a = 0; a < 2; a++) {
            const f16* qr = qb + a * 32 * DHEAD;
            qa[a][0] = *(const half8*)&qr[half * 8];
            qa[a][1] = *(const half8*)&qr[16 + half * 8];
            qa[a][2] = (half == 1) ? zero8 : *(const half8*)&qr[32];
        }
    }

    f32x16 O[4];                     // [a*2+t]: a = q-subtile, t = d 0..31 / 32..63
    #pragma unroll
    for (int i = 0; i < 16; i++) { O[0][i] = 0.f; O[1][i] = 0.f; O[2][i] = 0.f; O[3][i] = 0.f; }
    f32x16 Zc;                       // constant zero accumulator for S init
    #pragma unroll
    for (int i = 0; i < 16; i++) Zc[i] = 0.f;

    const f16* kb = k  + (size_t)bh * SEQ * DHEAD;   // [s][40]
    const f16* vb = vt + (size_t)bh * DHEAD * SEQ;   // [d][SEQ], keys perm'd

    // ---- staging indices: K 640 uint4 (r=idx/5,c=idx%5), V 640 (r=idx>>4,c=idx&15)
    int krow[3], kc[3], kdst[3], vrow[3], vc[3], vdst[3];
    #pragma unroll
    for (int u = 0; u < 3; u++) {
        int idx = tid + 256 * u;
        int r = (idx * 205) >> 10, c = idx - r * 5;
        krow[u] = r; kc[u] = c;
        kdst[u] = r * 64 + 8 * (c ^ (r & 7));
        int vr = idx >> 4, vcc = idx & 15;
        vrow[u] = vr; vc[u] = vcc;
        vdst[u] = 8192 + vr * 128 + 8 * (vcc ^ (vr & 7));
    }
    const bool full3 = (tid < 128);                  // third slot valid (idx < 640)

    // prefetch tile 0 into registers
    uint4 sk[3], sv[3];
    #pragma unroll
    for (int u = 0; u < 2; u++) {
        sk[u] = *(const uint4*)&kb[(size_t)krow[u] * DHEAD + kc[u] * 8];
        sv[u] = *(const uint4*)&vb[(size_t)vrow[u] * SEQ + vc[u] * 8];
    }
    if (full3) {
        sk[2] = *(const uint4*)&kb[(size_t)krow[2] * DHEAD + kc[2] * 8];
        sv[2] = *(const uint4*)&vb[(size_t)vrow[2] * SEQ + vc[2] * 8];
    }

    for (int j0 = 0; j0 < SEQ; j0 += 128) {
        const int stg = ((j0 >> 7) & 1) * 16384;
        #pragma unroll
        for (int u = 0; u < 2; u++) {
            *(uint4*)&ldsh[stg + kdst[u]] = sk[u];
            *(uint4*)&ldsh[stg + vdst[u]] = sv[u];
        }
        if (full3) {
            *(uint4*)&ldsh[stg + kdst[2]] = sk[2];
            *(uint4*)&ldsh[stg + vdst[2]] = sv[2];
        }
        __syncthreads();

        // prefetch next tile (lands during this tile's compute)
        if (j0 + 128 < SEQ) {
            const int jn = j0 + 128;
            #pragma unroll
            for (int u = 0; u < 2; u++) {
                sk[u] = *(const uint4*)&kb[(size_t)(jn + krow[u]) * DHEAD + kc[u] * 8];
                sv[u] = *(const uint4*)&vb[(size_t)vrow[u] * SEQ + jn + vc[u] * 8];
            }
            if (full3) {
                sk[2] = *(const uint4*)&kb[(size_t)(jn + krow[2]) * DHEAD + kc[2] * 8];
                sv[2] = *(const uint4*)&vb[(size_t)vrow[2] * SEQ + jn + vc[2] * 8];
            }
        }

        const f16* Kb = &ldsh[stg];
        const f16* Vb = &ldsh[stg + 8192];

        // ---- S^T = K . Q^T for both key-subtiles (A: keys 0..63, B: 64..127)
        half8 kfA[3], kfB[3];
        #pragma unroll
        for (int c = 0; c < 3; c++) {
            kfA[c] = *(const half8*)&Kb[(kh * 32 + m) * 64      + 8 * ((2 * c + half) ^ x7)];
            kfB[c] = *(const half8*)&Kb[(64 + kh * 32 + m) * 64 + 8 * ((2 * c + half) ^ x7)];
        }

        f32x16 SaA, SbA, SaB, SbB;
        __builtin_amdgcn_s_setprio(1);
        SaA = MFMA16(kfA[0], qa[0][0], Zc);  SbA = MFMA16(kfA[0], qa[1][0], Zc);
        SaA = MFMA16(kfA[1], qa[0][1], SaA); SbA = MFMA16(kfA[1], qa[1][1], SbA);
        SaA = MFMA16(kfA[2], qa[0][2], SaA); SbA = MFMA16(kfA[2], qa[1][2], SbA);
        SaB = MFMA16(kfB[0], qa[0][0], Zc);  SbB = MFMA16(kfB[0], qa[1][0], Zc);
        SaB = MFMA16(kfB[1], qa[0][1], SaB); SbB = MFMA16(kfB[1], qa[1][1], SbB);
        SaB = MFMA16(kfB[2], qa[0][2], SaB); SbB = MFMA16(kfB[2], qa[1][2], SbB);
        __builtin_amdgcn_s_setprio(0);

        // ---- subtile A: V frags, exp, PV (S(B) MFMAs overlap exp(A) issue)
        half8 vfA[2][2];
        #pragma unroll
        for (int c = 0; c < 2; c++) {
            vfA[c][0] = *(const half8*)&Vb[m * 128        + 8 * ((4 * kh + 2 * c + half) ^ x7)];
            vfA[c][1] = *(const half8*)&Vb[(32 + m) * 128 + 8 * ((4 * kh + 2 * c + half) ^ x7)];
        }
        H8 pa0, pa1, pb0, pb1;
        #pragma unroll
        for (int g = 0; g < 4; g++) {
            pa0.p2[g] = __builtin_amdgcn_cvt_pkrtz(EXP2F(SaA[2 * g]),     EXP2F(SaA[2 * g + 1]));
            pa1.p2[g] = __builtin_amdgcn_cvt_pkrtz(EXP2F(SaA[8 + 2 * g]), EXP2F(SaA[9 + 2 * g]));
            pb0.p2[g] = __builtin_amdgcn_cvt_pkrtz(EXP2F(SbA[2 * g]),     EXP2F(SbA[2 * g + 1]));
            pb1.p2[g] = __builtin_amdgcn_cvt_pkrtz(EXP2F(SbA[8 + 2 * g]), EXP2F(SbA[9 + 2 * g]));
        }
        __builtin_amdgcn_s_setprio(1);
        O[0] = MFMA16(pa0.h8, vfA[0][0], O[0]);
        O[1] = MFMA16(pa0.h8, vfA[0][1], O[1]);
        O[2] = MFMA16(pb0.h8, vfA[0][0], O[2]);
        O[3] = MFMA16(pb0.h8, vfA[0][1], O[3]);
        O[0] = MFMA16(pa1.h8, vfA[1][0], O[0]);
        O[1] = MFMA16(pa1.h8, vfA[1][1], O[1]);
        O[2] = MFMA16(pb1.h8, vfA[1][0], O[2]);
        O[3] = MFMA16(pb1.h8, vfA[1][1], O[3]);
        __builtin_amdgcn_s_setprio(0);

        // ---- subtile B: V frags, exp, PV (PV(A) MFMAs overlap exp(B) issue)
        half8 vfB[2][2];
        #pragma unroll
        for (int c = 0; c < 2; c++) {
            vfB[c][0] = *(const half8*)&Vb[m * 128        + 8 * ((8 + 4 * kh + 2 * c + half) ^ x7)];
            vfB[c][1] = *(const half8*)&Vb[(32 + m) * 128 + 8 * ((8 + 4 * kh + 2 * c + half) ^ x7)];
        }
        #pragma unroll
        for (int g = 0; g < 4; g++) {
            pa0.p2[g] = __builtin_amdgcn_cvt_pkrtz(EXP2F(SaB[2 * g]),     EXP2F(SaB[2 * g + 1]));
            pa1.p2[g] = __builtin_amdgcn_cvt_pkrtz(EXP2F(SaB[8 + 2 * g]), EXP2F(SaB[9 + 2 * g]));
            pb0.p2[g] = __builtin_amdgcn_cvt_pkrtz(EXP2F(SbB[2 * g]),     EXP2F(SbB[2 * g + 1]));
            pb1.p2[g] = __builtin_amdgcn_cvt_pkrtz(EXP2F(SbB[8 + 2 * g]), EXP2F(SbB[9 + 2 * g]));
        }
        __builtin_amdgcn_s_setprio(1);
        O[0] = MFMA16(pa0.h8, vfB[0][0], O[0]);
        O[1] = MFMA16(pa0.h8, vfB[0][1], O[1]);
        O[2] = MFMA16(pb0.h8, vfB[0][0], O[2]);
        O[3] = MFMA16(pb0.h8, vfB[0][1], O[3]);
        O[0] = MFMA16(pa1.h8, vfB[1][0], O[0]);
        O[1] = MFMA16(pa1.h8, vfB[1][1], O[1]);
        O[2] = MFMA16(pb1.h8, vfB[1][0], O[2]);
        O[3] = MFMA16(pb1.h8, vfB[1][1], O[3]);
        __builtin_amdgcn_s_setprio(0);
    }

    // ---- combine key-halves (exact: unnormalized sums), normalize, store y
    __syncthreads();
    if (kh == 1) {
        #pragma unroll
        for (int a = 0; a < 2; a++)
            #pragma unroll
            for (int t = 0; t < 2; t++)
                #pragma unroll
                for (int reg = 0; reg < 16; reg++) {
                    int row = 4 * half + (reg & 3) + 8 * (reg >> 2);
                    ldsf[(qp * 64 + a * 32 + row) * 66 + t * 32 + m] = O[a * 2 + t][reg];
                }
    }
    __syncthreads();
    if (kh == 0) {
        #pragma unroll
        for (int a = 0; a < 2; a++) {
            #pragma unroll
            for (int t = 0; t < 2; t++)
                #pragma unroll
                for (int reg = 0; reg < 16; reg++) {
                    int row = 4 * half + (reg & 3) + 8 * (reg >> 2);
                    O[a * 2 + t][reg] += ldsf[(qp * 64 + a * 32 + row) * 66 + t * 32 + m];
                }
            #pragma unroll
            for (int reg = 0; reg < 16; reg++) {
                float l = __shfl(O[a * 2 + 1][reg], 8 + 32 * half, 64);
                float rinv = 1.0f / l;
                int row = 4 * half + (reg & 3) + 8 * (reg >> 2);
                f16* yr = y + ((size_t)b * SEQ + q0 + qp * 64 + a * 32 + row) * INNER + h * DHEAD;
                yr[m] = (f16)(O[a * 2 + 0][reg] * rinv);                 // d 0..31
                if (m < 8) yr[32 + m] = (f16)(O[a * 2 + 1][reg] * rinv); // d 32..39
            }
        }
    }
}

// ---------------------------------------------------------------------------
// Output projection, fp16 MFMA: out = y @ Wout^T + bout, fp32 out.
// v3: next-k-step global->reg prefetch.
// ---------------------------------------------------------------------------
#define ASTR 72

__global__ __launch_bounds__(256)
void out_proj_kernel(const f16* __restrict__ y, const f16* __restrict__ wouth,
                     const float* __restrict__ bout, float* __restrict__ out)
{
    __shared__ f16 lds[(128 + 64) * ASTR];
    f16* As = lds;
    f16* Bs = lds + 128 * ASTR;

    const int tid = threadIdx.x;
    const int m0 = blockIdx.y * 128;
    const int n0 = blockIdx.x * 64;
    const int wave = tid >> 6, lane = tid & 63, m = lane & 31, half = lane >> 5;

    const int r0 = tid >> 3, c8 = tid & 7;

    f32x16 acc[2];
    #pragma unroll
    for (int i = 0; i < 16; i++) { acc[0][i] = 0.f; acc[1][i] = 0.f; }

    // prefetch k0 = 0
    uint4 pa[4], pb[2];
    #pragma unroll
    for (int u = 0; u < 4; u++)
        pa[u] = *(const uint4*)&y[(size_t)(m0 + r0 + 32 * u) * 320 + c8 * 8];
    #pragma unroll
    for (int u = 0; u < 2; u++)
        pb[u] = *(const uint4*)&wouth[(size_t)(n0 + r0 + 32 * u) * 320 + c8 * 8];

    for (int k0 = 0; k0 < 320; k0 += 64) {
        __syncthreads();
        #pragma unroll
        for (int u = 0; u < 4; u++)
            *(uint4*)&As[(r0 + 32 * u) * ASTR + c8 * 8] = pa[u];
        #pragma unroll
        for (int u = 0; u < 2; u++)
            *(uint4*)&Bs[(r0 + 32 * u) * ASTR + c8 * 8] = pb[u];
        __syncthreads();

        if (k0 + 64 < 320) {
            #pragma unroll
            for (int u = 0; u < 4; u++)
                pa[u] = *(const uint4*)&y[(size_t)(m0 + r0 + 32 * u) * 320 + k0 + 64 + c8 * 8];
            #pragma unroll
            for (int u = 0; u < 2; u++)
                pb[u] = *(const uint4*)&wouth[(size_t)(n0 + r0 + 32 * u) * 320 + k0 + 64 + c8 * 8];
        }

        #pragma unroll
        for (int c = 0; c < 4; c++) {
            half8 a  = *(const half8*)&As[(wave * 32 + m) * ASTR + c * 16 + half * 8];
            half8 b0 = *(const half8*)&Bs[m * ASTR + c * 16 + half * 8];
            half8 b1 = *(const half8*)&Bs[(32 + m) * ASTR + c * 16 + half * 8];
            acc[0] = MFMA16(a, b0, acc[0]);
            acc[1] = MFMA16(a, b1, acc[1]);
        }
    }

    #pragma unroll
    for (int nt = 0; nt < 2; nt++) {
        int n = n0 + nt * 32 + m;
        float bias = bout[n];
        #pragma unroll
        for (int reg = 0; reg < 16; reg++) {
            int crow = 4 * half + (reg & 3) + 8 * (reg >> 2);
            out[(size_t)(m0 + wave * 32 + crow) * 320 + n] = acc[nt][reg] + bias;
        }
    }
}

// ---------------------------------------------------------------------------
extern "C" void kernel_launch(void* const* d_in, const int* in_sizes, int n_in,
                              void* d_out, int out_size, void* d_ws, size_t ws_size,
                              hipStream_t stream)
{
    const float* x    = (const float*)d_in[0];
    const float* Wq   = (const float*)d_in[1];
    const float* Wk   = (const float*)d_in[2];
    const float* Wv   = (const float*)d_in[3];
    const float* Wout = (const float*)d_in[4];
    const float* bout = (const float*)d_in[5];
    float* out = (float*)d_out;

    unsigned char* ws = (unsigned char*)d_ws;
    f16* xh    = (f16*)(ws);                  //  5,242,880 B
    f16* wh    = (f16*)(ws +  5242880);       //    614,400 B
    f16* wouth = (f16*)(ws +  5857280);       //    204,800 B
    f16* qd    = (f16*)(ws +  6062080);       //  5,242,880 B
    f16* kd    = (f16*)(ws + 11304960);       //  5,242,880 B
    f16* vtd   = (f16*)(ws + 16547840);       //  5,242,880 B
    f16* yd    = (f16*)(ws + 21790720);       //  5,242,880 B

    convert_kernel <<<2960,         256, 0, stream>>>(x, Wq, Wk, Wv, Wout, xh, wh, wouth);
    qkv_gemm_kernel<<<dim3(5, 128), 256, 0, stream>>>(xh, wh, qd, kd, vtd);
    attn_kernel    <<<512,          256, 0, stream>>>(qd, kd, vtd, yd);
    out_proj_kernel<<<dim3(5, 64),  256, 0, stream>>>(yd, wouth, bout, out);
}

// Round 4
// 168.472 us; speedup vs baseline: 1.4041x; 1.4041x over previous
//
#include <hip/hip_runtime.h>

#define HEADS 8
#define DHEAD 40
#define SEQ   4096
#define BATCH 2
#define INNER 320
#define NBH   16
// softmax scale * log2(e), folded into Wq so p = exp2(s) is a single v_exp_f32
#define QSCALE ((float)(0.15811388300841897 * 1.4426950408889634))

typedef _Float16 f16;
typedef __attribute__((ext_vector_type(2)))  __fp16   fp16x2;  // cvt_pkrtz native type
typedef __attribute__((ext_vector_type(4)))  _Float16 half4;
typedef __attribute__((ext_vector_type(8)))  _Float16 half8;
typedef __attribute__((ext_vector_type(16))) float    f32x16;

#if __has_builtin(__builtin_amdgcn_exp2f)
#define EXP2F(x) __builtin_amdgcn_exp2f(x)
#else
#define EXP2F(x) exp2f(x)
#endif

#define MFMA16(a, b, c) __builtin_amdgcn_mfma_f32_32x32x16_f16(a, b, c, 0, 0, 0)

union H8 { half8 h8; fp16x2 p2[4]; uint4 u4; };

// ---------------------------------------------------------------------------
// Convert fp32 inputs to f16 once: x -> xh [8192][320]; Wq|Wk|Wv -> wh
// [960][320] (Wq pre-scaled by QSCALE); Wout -> wouth [320][320].
// ---------------------------------------------------------------------------
#define XN4   (BATCH * SEQ * INNER / 4)   // 655360
#define WQKV4 (3 * INNER * INNER / 4)     // 76800
#define WOUT4 (INNER * INNER / 4)         // 25600
#define CONV_TOTAL (XN4 + WQKV4 + WOUT4)  // 757760

__global__ __launch_bounds__(256)
void convert_kernel(const float* __restrict__ x,
                    const float* __restrict__ Wq,
                    const float* __restrict__ Wk,
                    const float* __restrict__ Wv,
                    const float* __restrict__ Wout,
                    f16* __restrict__ xh, f16* __restrict__ wh,
                    f16* __restrict__ wouth)
{
    int i = blockIdx.x * 256 + threadIdx.x;
    if (i >= CONV_TOTAL) return;
    float4 v;
    f16* dst;
    float sc = 1.0f;
    if (i < XN4) {
        v = ((const float4*)x)[i];
        dst = xh + 4 * (size_t)i;
    } else if (i < XN4 + WQKV4) {
        int j = i - XN4;                       // float4 idx in concat [960][320]
        if (j < 25600)      { v = ((const float4*)Wq)[j]; sc = QSCALE; }
        else if (j < 51200) { v = ((const float4*)Wk)[j - 25600]; }
        else                { v = ((const float4*)Wv)[j - 51200]; }
        dst = wh + 4 * (size_t)j;
    } else {
        int j = i - XN4 - WQKV4;
        v = ((const float4*)Wout)[j];
        dst = wouth + 4 * (size_t)j;
    }
    H8 u;
    u.p2[0] = __builtin_amdgcn_cvt_pkrtz(v.x * sc, v.y * sc);
    u.p2[1] = __builtin_amdgcn_cvt_pkrtz(v.z * sc, v.w * sc);
    *(uint2*)dst = make_uint2(u.u4.x, u.u4.y);
}

// ---------------------------------------------------------------------------
// Merged QKV projection, fp16 MFMA (r2 structure, no reg-prefetch).
// NEW epilogue layouts for the barrier-free attention:
//   K -> Kt[bh][chunk 0..4][s][8 halves]  (frag-major: a K MFMA fragment is
//        32 consecutive 16B lane-reads)
//   V -> Vt2[bh][s8 0..511][d 0..39][8 keys], keys permuted [0,2,1,3] per
//        16-group (matches S^T-register P fragment key order)
// Q stays [bh][s][40].
// ---------------------------------------------------------------------------
#define QSTR 72

__global__ __launch_bounds__(256)
void qkv_gemm_kernel(const f16* __restrict__ xh, const f16* __restrict__ wh,
                     f16* __restrict__ q, f16* __restrict__ kt,
                     f16* __restrict__ vt)
{
    __shared__ f16 lds[(64 + 192) * QSTR];   // As [64][72] + Bs [192][72] = 36864 B
    f16* As = lds;
    f16* Bs = lds + 64 * QSTR;

    const int tid = threadIdx.x;
    const int nb0 = blockIdx.x * 64;
    const int m0  = blockIdx.y * 64;
    const int wave = tid >> 6, lane = tid & 63, m = lane & 31, half = lane >> 5;
    const int mw = wave >> 1, nw = wave & 1;

    f32x16 acc[3];
    #pragma unroll
    for (int i = 0; i < 16; i++) { acc[0][i] = 0.f; acc[1][i] = 0.f; acc[2][i] = 0.f; }

    for (int k0 = 0; k0 < 320; k0 += 64) {
        __syncthreads();
        #pragma unroll
        for (int u = 0; u < 2; u++) {        // A: 64r x 64k = 512 uint4
            int idx = tid + 256 * u;
            int r = idx >> 3, c8 = idx & 7;
            *(uint4*)&As[r * QSTR + c8 * 8] =
                *(const uint4*)&xh[(size_t)(m0 + r) * 320 + k0 + c8 * 8];
        }
        #pragma unroll
        for (int u = 0; u < 6; u++) {        // B: 192r x 64k = 1536 uint4
            int idx = tid + 256 * u;
            int r = idx >> 3, c8 = idx & 7;
            int wr = (r >> 6) * 320 + nb0 + (r & 63);
            *(uint4*)&Bs[r * QSTR + c8 * 8] =
                *(const uint4*)&wh[(size_t)wr * 320 + k0 + c8 * 8];
        }
        __syncthreads();
        #pragma unroll
        for (int c = 0; c < 4; c++) {
            half8 a = *(const half8*)&As[(mw * 32 + m) * QSTR + c * 16 + half * 8];
            #pragma unroll
            for (int t = 0; t < 3; t++) {
                half8 bf = *(const half8*)&Bs[(nw * 96 + t * 32 + m) * QSTR + c * 16 + half * 8];
                acc[t] = MFMA16(a, bf, acc[t]);
            }
        }
    }

    const int b = m0 >> 12, s0 = m0 & 4095;

    // q / k scatter (subtiles st = nw*3+t < 4)
    #pragma unroll
    for (int t = 0; t < 3; t++) {
        int st = nw * 3 + t;
        if (st < 4) {
            int col = nb0 + (st & 1) * 32 + m;
            int h  = (col * 205) >> 13;          // == col/40 for col<328
            int dd = col - h * 40;
            #pragma unroll
            for (int reg = 0; reg < 16; reg++) {
                int crow = 4 * half + (reg & 3) + 8 * (reg >> 2);
                int mg = m0 + mw * 32 + crow;
                int bb = mg >> 12, s = mg & 4095;
                if (st < 2)
                    q[((size_t)(bb * 8 + h) * SEQ + s) * DHEAD + dd] = (f16)acc[t][reg];
                else
                    kt[(((size_t)(bb * 8 + h) * 5 + (dd >> 3)) * SEQ + s) * 8 + (dd & 7)]
                        = (f16)acc[t][reg];
            }
        }
    }

    // v transpose: subtiles st 4,5 (nw==1, t=1,2) -> Ct [64 vcol][72]
    __syncthreads();
    f16* Ct = lds;
    if (nw == 1) {
        #pragma unroll
        for (int t = 1; t < 3; t++) {
            int vr0 = (t - 1) * 32 + m;
            #pragma unroll
            for (int g = 0; g < 4; g++) {
                half4 hh;
                hh.x = (f16)acc[t][4 * g + 0]; hh.y = (f16)acc[t][4 * g + 1];
                hh.z = (f16)acc[t][4 * g + 2]; hh.w = (f16)acc[t][4 * g + 3];
                *(half4*)&Ct[vr0 * QSTR + mw * 32 + 8 * g + 4 * half] = hh;
            }
        }
    }
    __syncthreads();
    // write-out to Vt2: iterate (c4 outer, rl inner) so consecutive threads
    // walk d (16B stride in the new layout) -> near-coalesced 8B stores
    #pragma unroll
    for (int u = 0; u < 4; u++) {            // 16 c4 x 64 rl = 1024 uint2
        int idx = tid + 256 * u;
        int c4 = idx >> 6, rl = idx & 63;
        int col = nb0 + rl;
        int h  = (col * 205) >> 13;
        int dd = col - h * 40;
        int w4 = c4 & 3;
        int c4p = (c4 & ~3) | ((w4 == 1) ? 2 : (w4 == 2) ? 1 : w4);
        *(uint2*)&vt[(((size_t)(b * 8 + h) * 512 + (s0 >> 3) + (c4p >> 1)) * 40 + dd) * 8
                     + (c4p & 1) * 4] =
            *(const uint2*)&Ct[rl * QSTR + c4 * 4];
    }
}

// ---------------------------------------------------------------------------
// Flash attention v4: fp16 MFMA, P in registers (S^T trick), ZERO LDS and
// ZERO barriers in the kernel. K and V MFMA fragments load DIRECTLY from
// global in frag-major layouts (Kt / Vt2 above): every lane-read is 16B at
// 16B stride -> 2x512B segments per instruction, fully coalesced (fixes
// r1's scattered-lane failure). One wave = 32 q-rows x all 64 keys/iter:
//   6 S-MFMA (two 32-key chains) + 32 exp + 8 PV-MFMA.
// Waves are fully independent -> the 2 waves/SIMD drift in phase and one
// wave's MFMAs overlap the other's exp burst; within a wave, S2's chain
// overlaps exp(S1) and PV(S1-half) overlaps exp(S2).
// Pads by construction:  K dk 40..47: kf[2] half=1 re-reads chunk 4
// (finite) x qa[2]zero = 0.  V d-tile-2: lanes m<8 read d=32+m, m>8 clamp
// to d=39 (finite garbage -> unused O1 cols 9..31), m==8 -> ones8 via
// cndmask => O1 col 8 accumulates exact f32 row sums (same math as r2).
// kf double-buffered (one tile ahead); vf issued at iter top, consumed
// after S+exp (~500 cyc of cover). launch_bounds (256,2): 256-VGPR cap,
// ~230 used, no spill (r3 lesson). 512 blocks = exactly 2/CU.
// ---------------------------------------------------------------------------
__global__ __launch_bounds__(256, 2)
void attn_kernel(const f16* __restrict__ q, const f16* __restrict__ kt,
                 const f16* __restrict__ vt, f16* __restrict__ y)
{
    const int tid = threadIdx.x;
    const int blk = blockIdx.x;
    const int xcd = blk & 7, slot = blk >> 3;        // XCD swizzle: 2 bh per XCD
    const int bh = xcd * 2 + (slot >> 5), qt = slot & 31;
    const int b = bh >> 3, h = bh & 7;
    const int q0 = qt * 128;
    const int wave = tid >> 6, lane = tid & 63, m = lane & 31, half = lane >> 5;

    half8 zero8, ones8;
    #pragma unroll
    for (int j = 0; j < 8; j++) { zero8[j] = (f16)0.0f; ones8[j] = (f16)1.0f; }

    // ---- Q B-fragments: rows q0 + wave*32 + m (d 40..47 -> 0)
    half8 qa[3];
    {
        const f16* qb = q + ((size_t)bh * SEQ + q0 + wave * 32 + m) * DHEAD;
        qa[0] = *(const half8*)&qb[half * 8];
        qa[1] = *(const half8*)&qb[16 + half * 8];
        qa[2] = (half == 1) ? zero8 : *(const half8*)&qb[32];
    }

    f32x16 O0, O1, Zc;
    #pragma unroll
    for (int i = 0; i < 16; i++) { O0[i] = 0.f; O1[i] = 0.f; Zc[i] = 0.f; }

    // ---- per-lane fragment base pointers
    const f16* kbh = kt + (size_t)bh * 5 * SEQ * 8;
    const f16* kbase0 = kbh + ((size_t)(0 + half) * SEQ + m) * 8;   // chunks {0,1}
    const f16* kbase1 = kbh + ((size_t)(2 + half) * SEQ + m) * 8;   // chunks {2,3}
    const f16* kbase2 = kbh + ((size_t)4 * SEQ + m) * 8;            // chunk 4 (both)
    const f16* vbh = vt + (size_t)bh * 512 * 320;
    const int d1 = (m < 8) ? (32 + m) : 39;
    const f16* vbase0 = vbh + (size_t)half * 320 + m * 8;           // t=0: d = m
    const f16* vbase1 = vbh + (size_t)half * 320 + d1 * 8;          // t=1

#define LOADK(kf, j0) do {                                                    \
    const f16* p0_ = kbase0 + (size_t)(j0) * 8;                               \
    const f16* p1_ = kbase1 + (size_t)(j0) * 8;                               \
    const f16* p2_ = kbase2 + (size_t)(j0) * 8;                               \
    kf[0][0] = *(const half8*)p0_;  kf[0][1] = *(const half8*)(p0_ + 256);    \
    kf[1][0] = *(const half8*)p1_;  kf[1][1] = *(const half8*)(p1_ + 256);    \
    kf[2][0] = *(const half8*)p2_;  kf[2][1] = *(const half8*)(p2_ + 256);    \
} while (0)

#define LOADV(vf, j0) do {                                                    \
    const f16* v0_ = vbase0 + (size_t)(j0) * 40;                              \
    const f16* v1_ = vbase1 + (size_t)(j0) * 40;                              \
    vf[0][0] = *(const half8*)v0_;           vf[0][1] = *(const half8*)v1_;   \
    vf[1][0] = *(const half8*)(v0_ + 640);   vf[1][1] = *(const half8*)(v1_ + 640);  \
    vf[2][0] = *(const half8*)(v0_ + 1280);  vf[2][1] = *(const half8*)(v1_ + 1280); \
    vf[3][0] = *(const half8*)(v0_ + 1920);  vf[3][1] = *(const half8*)(v1_ + 1920); \
} while (0)

#define BODY(kf, j0) do {                                                     \
    LOADV(vf, j0);                                                            \
    f32x16 S1, S2;                                                            \
    __builtin_amdgcn_s_setprio(1);                                            \
    S1 = MFMA16(kf[0][0], qa[0], Zc);  S2 = MFMA16(kf[0][1], qa[0], Zc);      \
    S1 = MFMA16(kf[1][0], qa[1], S1);  S2 = MFMA16(kf[1][1], qa[1], S2);      \
    S1 = MFMA16(kf[2][0], qa[2], S1);  S2 = MFMA16(kf[2][1], qa[2], S2);      \
    __builtin_amdgcn_s_setprio(0);                                            \
    H8 p0, p1, p2, p3;                                                        \
    _Pragma("unroll")                                                         \
    for (int g = 0; g < 4; g++) {                                             \
        p0.p2[g] = __builtin_amdgcn_cvt_pkrtz(EXP2F(S1[2*g]),   EXP2F(S1[2*g+1]));   \
        p1.p2[g] = __builtin_amdgcn_cvt_pkrtz(EXP2F(S1[8+2*g]), EXP2F(S1[9+2*g]));   \
        p2.p2[g] = __builtin_amdgcn_cvt_pkrtz(EXP2F(S2[2*g]),   EXP2F(S2[2*g+1]));   \
        p3.p2[g] = __builtin_amdgcn_cvt_pkrtz(EXP2F(S2[8+2*g]), EXP2F(S2[9+2*g]));   \
    }                                                                         \
    half8 w0 = (m == 8) ? ones8 : vf[0][1];                                   \
    half8 w1 = (m == 8) ? ones8 : vf[1][1];                                   \
    half8 w2 = (m == 8) ? ones8 : vf[2][1];                                   \
    half8 w3 = (m == 8) ? ones8 : vf[3][1];                                   \
    __builtin_amdgcn_s_setprio(1);                                            \
    O0 = MFMA16(p0.h8, vf[0][0], O0);  O1 = MFMA16(p0.h8, w0, O1);            \
    O0 = MFMA16(p1.h8, vf[1][0], O0);  O1 = MFMA16(p1.h8, w1, O1);            \
    O0 = MFMA16(p2.h8, vf[2][0], O0);  O1 = MFMA16(p2.h8, w2, O1);            \
    O0 = MFMA16(p3.h8, vf[3][0], O0);  O1 = MFMA16(p3.h8, w3, O1);            \
    __builtin_amdgcn_s_setprio(0);                                            \
} while (0)

    half8 kfA[3][2], kfB[3][2], vf[4][2];
    LOADK(kfA, 0);
    for (int j0 = 0; j0 < SEQ; j0 += 128) {
        LOADK(kfB, j0 + 64);
        BODY(kfA, j0);
        if (j0 + 128 < SEQ) { LOADK(kfA, j0 + 128); }
        BODY(kfB, j0 + 64);
    }

    // ---- normalize by row sums (O1 col 8) and store y
    #pragma unroll
    for (int reg = 0; reg < 16; reg++) {
        float l = __shfl(O1[reg], 8 + 32 * half, 64);
        float rinv = 1.0f / l;
        int row = 4 * half + (reg & 3) + 8 * (reg >> 2);
        f16* yr = y + ((size_t)b * SEQ + q0 + wave * 32 + row) * INNER + h * DHEAD;
        yr[m] = (f16)(O0[reg] * rinv);                 // d 0..31
        if (m < 8) yr[32 + m] = (f16)(O1[reg] * rinv); // d 32..39
    }
#undef LOADK
#undef LOADV
#undef BODY
}

// ---------------------------------------------------------------------------
// Output projection, fp16 MFMA: out = y @ Wout^T + bout, fp32 out.
// (r2 structure, no reg-prefetch — r3's prefetch regressed the GEMMs.)
// ---------------------------------------------------------------------------
#define ASTR 72

__global__ __launch_bounds__(256)
void out_proj_kernel(const f16* __restrict__ y, const f16* __restrict__ wouth,
                     const float* __restrict__ bout, float* __restrict__ out)
{
    __shared__ f16 lds[(128 + 64) * ASTR];
    f16* As = lds;
    f16* Bs = lds + 128 * ASTR;

    const int tid = threadIdx.x;
    const int m0 = blockIdx.y * 128;
    const int n0 = blockIdx.x * 64;
    const int wave = tid >> 6, lane = tid & 63, m = lane & 31, half = lane >> 5;

    f32x16 acc[2];
    #pragma unroll
    for (int i = 0; i < 16; i++) { acc[0][i] = 0.f; acc[1][i] = 0.f; }

    for (int k0 = 0; k0 < 320; k0 += 64) {
        __syncthreads();
        #pragma unroll
        for (int u = 0; u < 4; u++) {
            int idx = tid + 256 * u;
            int r = idx >> 3, c8 = idx & 7;
            *(uint4*)&As[r * ASTR + c8 * 8] =
                *(const uint4*)&y[(size_t)(m0 + r) * 320 + k0 + c8 * 8];
        }
        #pragma unroll
        for (int u = 0; u < 2; u++) {
            int idx = tid + 256 * u;
            int r = idx >> 3, c8 = idx & 7;
            *(uint4*)&Bs[r * ASTR + c8 * 8] =
                *(const uint4*)&wouth[(size_t)(n0 + r) * 320 + k0 + c8 * 8];
        }
        __syncthreads();
        #pragma unroll
        for (int c = 0; c < 4; c++) {
            half8 a  = *(const half8*)&As[(wave * 32 + m) * ASTR + c * 16 + half * 8];
            half8 b0 = *(const half8*)&Bs[m * ASTR + c * 16 + half * 8];
            half8 b1 = *(const half8*)&Bs[(32 + m) * ASTR + c * 16 + half * 8];
            acc[0] = MFMA16(a, b0, acc[0]);
            acc[1] = MFMA16(a, b1, acc[1]);
        }
    }

    #pragma unroll
    for (int nt = 0; nt < 2; nt++) {
        int n = n0 + nt * 32 + m;
        float bias = bout[n];
        #pragma unroll
        for (int reg = 0; reg < 16; reg++) {
            int crow = 4 * half + (reg & 3) + 8 * (reg >> 2);
            out[(size_t)(m0 + wave * 32 + crow) * 320 + n] = acc[nt][reg] + bias;
        }
    }
}

// ---------------------------------------------------------------------------
extern "C" void kernel_launch(void* const* d_in, const int* in_sizes, int n_in,
                              void* d_out, int out_size, void* d_ws, size_t ws_size,
                              hipStream_t stream)
{
    const float* x    = (const float*)d_in[0];
    const float* Wq   = (const float*)d_in[1];
    const float* Wk   = (const float*)d_in[2];
    const float* Wv   = (const float*)d_in[3];
    const float* Wout = (const float*)d_in[4];
    const float* bout = (const float*)d_in[5];
    float* out = (float*)d_out;

    unsigned char* ws = (unsigned char*)d_ws;
    f16* xh    = (f16*)(ws);                  //  5,242,880 B
    f16* wh    = (f16*)(ws +  5242880);       //    614,400 B
    f16* wouth = (f16*)(ws +  5857280);       //    204,800 B
    f16* qd    = (f16*)(ws +  6062080);       //  5,242,880 B
    f16* ktd   = (f16*)(ws + 11304960);       //  5,242,880 B  [bh][5][4096][8]
    f16* vtd   = (f16*)(ws + 16547840);       //  5,242,880 B  [bh][512][40][8]
    f16* yd    = (f16*)(ws + 21790720);       //  5,242,880 B

    convert_kernel <<<2960,         256, 0, stream>>>(x, Wq, Wk, Wv, Wout, xh, wh, wouth);
    qkv_gemm_kernel<<<dim3(5, 128), 256, 0, stream>>>(xh, wh, qd, ktd, vtd);
    attn_kernel    <<<512,          256, 0, stream>>>(qd, ktd, vtd, yd);
    out_proj_kernel<<<dim3(5, 64),  256, 0, stream>>>(yd, wouth, bout, out);
}